// Round 7
// baseline (33.731 us; speedup 1.0000x reference)
//
#include <hip/hip_runtime.h>

#define NPTS 2048
#define NCP  32
#define P    4   // consecutive points per thread (float4 stores)
#define GB   2   // batches per block

typedef float v2f __attribute__((ext_vector_type(2)));

// v_pk_fma_f32: d = a*b + c, two independent fp32 lanes per instruction.
// Full-rate on gfx950 (this is how the 157 TF fp32 peak is defined).
__device__ __forceinline__ v2f pkfma(v2f a, v2f b, v2f c) {
    v2f d;
    asm("v_pk_fma_f32 %0, %1, %2, %3" : "=v"(d) : "v"(a), "v"(b), "v"(c));
    return d;
}

// Binomial coefficients C(31, i) (exact)
static __device__ const float C31[NCP] = {
    1.f, 31.f, 465.f, 4495.f, 31465.f, 169911.f, 736281.f, 2629575.f,
    7888725.f, 20160075.f, 44352165.f, 84672315.f, 141120525.f, 206253075.f,
    265182525.f, 300540195.f, 300540195.f, 265182525.f, 206253075.f, 141120525.f,
    84672315.f, 44352165.f, 20160075.f, 7888725.f, 2629575.f, 736281.f,
    169911.f, 31465.f, 4495.f, 465.f, 31.f, 1.f
};

// Clamped knot vector value for knot index i (0..35): 4 zeros, interior
// (i-3)/29, 4 ones.
__device__ __forceinline__ float knq(int i) {
    int m = i - 3;
    m = m < 0 ? 0 : m;
    return (m >= 29) ? 1.0f : (float)m * (float)(1.0 / 29.0);
}

// P=4 x GB=2, 6 waves/SIMD. VALU-issue-bound kernel -> pack all x/y FMA
// streams into v_pk_fma_f32 (halves the dominant instruction count).
// LDS: bezier kept as (x,y) pairs; bspline+nurbs interleaved as
// {bs.x,bs.y,nc.x,nc.y} float4 so the sparse inner step is 1 ds_read_b128
// + 2 pk_fma. Accumulation order per component identical to R2/R6.
__global__ void __launch_bounds__(256, 6) fused_kernel(
    const float* __restrict__ bspline_cp, const float* __restrict__ nurbs_cp,
    const float* __restrict__ nurbs_w, const float* __restrict__ bezier_cp,
    float* __restrict__ out, int B) {
    const int tid = threadIdx.x;
    const int n0  = (blockIdx.x * 256 + tid) * P;   // first of this thread's 4 points
    const int b0  = blockIdx.y * GB;

    __shared__ float4 s_bn[GB * NCP];       // {bs.x, bs.y, nc.x, nc.y}
    __shared__ float  s_bz[GB * NCP * 2];   // (x,y) pairs
    __shared__ float  s_w [GB * NCP];
    {
        // 256 floats of interleaved bs/nc: one float per thread
        const int g = tid >> 7, rem = tid & 127;
        const int i = rem >> 2, c = rem & 3;
        const float* src = (c < 2) ? bspline_cp : nurbs_cp;
        reinterpret_cast<float*>(s_bn)[tid] =
            src[(size_t)(b0 + g) * NCP * 2 + i * 2 + (c & 1)];
        if (tid < GB * NCP * 2)
            s_bz[tid] = bezier_cp[(size_t)b0 * NCP * 2 + tid];
        if (tid < GB * NCP)
            s_w[tid] = nurbs_w[(size_t)b0 * NCP + tid];
    }
    __syncthreads();

    const unsigned cs = (unsigned)B * 2u * NPTS;    // per-curve output stride

    // ---- Phase A: per-point t -> span, de Boor basis, bernstein log-params
    int   sp_[P];
    float bv[P][4];
    float dd[P], e0[P];
#pragma unroll
    for (int p = 0; p < P; ++p) {
        const float t = (float)((double)(n0 + p) * (1.0 / (double)(NPTS - 1)));
        const float lu = __builtin_amdgcn_logf(fmaxf(t, 1e-30f));
        const float lv = __builtin_amdgcn_logf(fmaxf(1.0f - t, 1e-30f));
        dd[p] = lu - lv;
        e0[p] = 31.0f * lv;
        int s = (int)(t * 29.0f);
        s = s < 28 ? s : 28;
        sp_[p] = s;
        const int j = s + 3;             // knot-span: U[j] <= t < U[j+1]
        const float L1 = t - knq(j);
        const float R1 = knq(j + 1) - t;
        const float L2 = t - knq(j - 1);
        const float R2 = knq(j + 2) - t;
        const float L3 = t - knq(j - 2);
        const float R3 = knq(j + 3) - t;
        float N0, N1, N2, N3, tmp, sv;
        tmp = __builtin_amdgcn_rcpf(R1 + L1);
        N0 = R1 * tmp;
        N1 = L1 * tmp;
        tmp = N0 * __builtin_amdgcn_rcpf(R1 + L2);
        N0 = R1 * tmp;
        sv = L2 * tmp;
        tmp = N1 * __builtin_amdgcn_rcpf(R2 + L1);
        N1 = fmaf(R2, tmp, sv);
        N2 = L1 * tmp;
        tmp = N0 * __builtin_amdgcn_rcpf(R1 + L3);
        N0 = R1 * tmp;
        sv = L3 * tmp;
        tmp = N1 * __builtin_amdgcn_rcpf(R2 + L2);
        N1 = fmaf(R2, tmp, sv);
        sv = L2 * tmp;
        tmp = N2 * __builtin_amdgcn_rcpf(R3 + L1);
        N2 = fmaf(R3, tmp, sv);
        N3 = L1 * tmp;
        bv[p][0] = N0; bv[p][1] = N1; bv[p][2] = N2; bv[p][3] = N3;
    }

    // ---- Phase B: B-spline + NURBS sparse 4-term dots (packed x,y) ----
#pragma unroll
    for (int g = 0; g < GB; ++g) {
        v2f ob[P], on[P];                 // packed (x,y) results
#pragma unroll
        for (int p = 0; p < P; ++p) {
            v2f sb = {0.f, 0.f}, sn = {0.f, 0.f};
            float den = 0.f;
#pragma unroll
            for (int k = 0; k < 4; ++k) {
                const int idx = sp_[p] + k;
                const float c = bv[p][k];
                const float4 q = s_bn[g * NCP + idx];   // bs.x bs.y nc.x nc.y
                v2f cb; cb[0] = q.x; cb[1] = q.y;
                v2f cn; cn[0] = q.z; cn[1] = q.w;
                v2f cc; cc[0] = c;   cc[1] = c;
                sb = pkfma(cc, cb, sb);
                const float wb = c * s_w[g * 32 + idx];
                den += wb;
                v2f ww; ww[0] = wb; ww[1] = wb;
                sn = pkfma(ww, cn, sn);
            }
            const float inv = __builtin_amdgcn_rcpf(den + 1e-8f);
            v2f vi; vi[0] = inv; vi[1] = inv;
            ob[p] = sb;
            on[p][0] = sn[0] * vi[0];
            on[p][1] = sn[1] * vi[1];
        }
        const unsigned base = (unsigned)(b0 + g) * 2u * NPTS + (unsigned)n0;
        *reinterpret_cast<float4*>(&out[base]) =
            make_float4(ob[0][0], ob[1][0], ob[2][0], ob[3][0]);
        *reinterpret_cast<float4*>(&out[base + NPTS]) =
            make_float4(ob[0][1], ob[1][1], ob[2][1], ob[3][1]);
        *reinterpret_cast<float4*>(&out[cs + base]) =
            make_float4(on[0][0], on[1][0], on[2][0], on[3][0]);
        *reinterpret_cast<float4*>(&out[cs + base + NPTS]) =
            make_float4(on[0][1], on[1][1], on[2][1], on[3][1]);
    }

    // ---- Phase C: Bezier dense 32-term dot (packed x,y accumulators) ----
    v2f acc[GB][P];
#pragma unroll
    for (int g = 0; g < GB; ++g)
#pragma unroll
        for (int p = 0; p < P; ++p) { acc[g][p][0] = 0.f; acc[g][p][1] = 0.f; }
#pragma unroll
    for (int i = 0; i < NCP; i += 2) {
        float ba[P], bb[P];
#pragma unroll
        for (int p = 0; p < P; ++p) {
            ba[p] = C31[i]     * __builtin_amdgcn_exp2f(fmaf((float)i,       dd[p], e0[p]));
            bb[p] = C31[i + 1] * __builtin_amdgcn_exp2f(fmaf((float)(i + 1), dd[p], e0[p]));
        }
#pragma unroll
        for (int g = 0; g < GB; ++g) {
            // wave-uniform broadcast b128: (x_i, y_i, x_{i+1}, y_{i+1})
            const float4 c = *reinterpret_cast<const float4*>(&s_bz[g * 64 + 2 * i]);
            v2f c0; c0[0] = c.x; c0[1] = c.y;
            v2f c1; c1[0] = c.z; c1[1] = c.w;
#pragma unroll
            for (int p = 0; p < P; ++p) {
                v2f va; va[0] = ba[p]; va[1] = ba[p];
                v2f vb; vb[0] = bb[p]; vb[1] = bb[p];
                // same order as scalar version: bb-term first, then ba-term
                acc[g][p] = pkfma(vb, c1, acc[g][p]);
                acc[g][p] = pkfma(va, c0, acc[g][p]);
            }
        }
    }
#pragma unroll
    for (int g = 0; g < GB; ++g) {
        const unsigned base = 2u * cs + (unsigned)(b0 + g) * 2u * NPTS + (unsigned)n0;
        *reinterpret_cast<float4*>(&out[base]) =
            make_float4(acc[g][0][0], acc[g][1][0], acc[g][2][0], acc[g][3][0]);
        *reinterpret_cast<float4*>(&out[base + NPTS]) =
            make_float4(acc[g][0][1], acc[g][1][1], acc[g][2][1], acc[g][3][1]);
    }
}

extern "C" void kernel_launch(void* const* d_in, const int* in_sizes, int n_in,
                              void* d_out, int out_size, void* d_ws, size_t ws_size,
                              hipStream_t stream) {
    const float* bspline_cp = (const float*)d_in[0];
    const float* nurbs_cp   = (const float*)d_in[1];
    const float* nurbs_w    = (const float*)d_in[2];
    const float* bezier_cp  = (const float*)d_in[3];
    float* out = (float*)d_out;

    const int B = in_sizes[2] / NCP;              // 2048

    hipLaunchKernelGGL(fused_kernel, dim3(NPTS / (256 * P), B / GB), dim3(256), 0, stream,
                       bspline_cp, nurbs_cp, nurbs_w, bezier_cp, out, B);
}